// Round 7
// baseline (197.377 us; speedup 1.0000x reference)
//
#include <hip/hip_runtime.h>
#include <hip/hip_bf16.h>
#include <math.h>

#define B_   64
#define N_   100
#define K_   16
#define C_   1024
#define R_   8
#define BN_  6400
#define E_   102400

typedef __attribute__((ext_vector_type(8))) short bf16x8;
typedef __attribute__((ext_vector_type(4))) float f32x4;

__device__ __forceinline__ float bf2f(ushort h) {
    union { uint32_t u; float f; } v; v.u = ((uint32_t)h) << 16; return v.f;
}
__device__ __forceinline__ ushort f2bf(float f) {
    union { float f; uint32_t u; } v; v.f = f;
    uint32_t r = v.u + 0x7FFFu + ((v.u >> 16) & 1u);   // RNE
    return (ushort)(r >> 16);
}

__device__ __forceinline__ void gload_lds16(const void* g, void* l) {
    __builtin_amdgcn_global_load_lds(
        (const __attribute__((address_space(1))) void*)g,
        (__attribute__((address_space(3))) void*)l, 16, 0, 0);
}

// --------------------------------------------------------------------------
// Edge weights, both layers.  Layout: w[r][e]  (coalesced store AND read).
// --------------------------------------------------------------------------
__global__ __launch_bounds__(256) void edge_weights_kernel(
        const float* __restrict__ centre, const int* __restrict__ nbr_idx,
        const float* __restrict__ graph_w,
        const float* __restrict__ mr1, const float* __restrict__ mt1,
        const float* __restrict__ pr1, const float* __restrict__ pt1,
        const float* __restrict__ mr2, const float* __restrict__ mt2,
        const float* __restrict__ pr2, const float* __restrict__ pt2,
        float* __restrict__ w1, float* __restrict__ w2) {
    int e = blockIdx.x * blockDim.x + threadIdx.x;
    if (e >= E_) return;
    int n = e / K_;
    int b = n / N_;
    int fn = b * N_ + nbr_idx[e];
    float dx = centre[2*n]   - centre[2*fn];
    float dy = centre[2*n+1] - centre[2*fn+1];
    float rho   = sqrtf(dx*dx + dy*dy);
    float theta = atan2f(dx, dy);
    const float TWO_PI = 6.28318530717958647692f;
    {
        float w[R_]; float s = 0.f;
        #pragma unroll
        for (int r = 0; r < R_; ++r) {
            float dr = rho - mr1[r];
            float wr = expf(-0.5f * dr * dr / (1e-14f + pr1[r]*pr1[r]));
            float fa = fabsf(theta - mt1[r]);
            float mi = fminf(fa, fabsf(TWO_PI - fa));
            float wt = expf(-0.5f * mi * mi / (1e-14f + pt1[r]*pt1[r]));
            float ww = wr * wt;
            if (isnan(ww)) ww = 0.f;
            w[r] = ww; s += ww;
        }
        float gw = graph_w[e];
        #pragma unroll
        for (int r = 0; r < R_; ++r) w1[(size_t)r * E_ + e] = gw * (w[r] / s);
    }
    {
        float w[R_]; float s = 0.f;
        #pragma unroll
        for (int r = 0; r < R_; ++r) {
            float dr = rho - mr2[r];
            float wr = expf(-0.5f * dr * dr / (1e-14f + pr2[r]*pr2[r]));
            float fa = fabsf(theta - mt2[r]);
            float mi = fminf(fa, fabsf(TWO_PI - fa));
            float wt = expf(-0.5f * mi * mi / (1e-14f + pt2[r]*pt2[r]));
            float ww = wr * wt;
            if (isnan(ww)) ww = 0.f;
            w[r] = ww; s += ww;
        }
        #pragma unroll
        for (int r = 0; r < R_; ++r) w2[(size_t)r * E_ + e] = w[r] / s;
    }
}

// --------------------------------------------------------------------------
// X fp32 -> bf16
// --------------------------------------------------------------------------
__global__ __launch_bounds__(256) void cast_x_kernel(
        const float* __restrict__ X, ushort* __restrict__ Xb) {
    int i = (blockIdx.x * 256 + threadIdx.x) * 4;
    float4 v = *(const float4*)&X[i];
    ushort4 o; o.x = f2bf(v.x); o.y = f2bf(v.y); o.z = f2bf(v.z); o.w = f2bf(v.w);
    *(ushort4*)&Xb[i] = o;
}

// --------------------------------------------------------------------------
// conv_w [8][1024][128] fp32 -> Wt[j][c] bf16, LDS-tiled transpose.
// --------------------------------------------------------------------------
__global__ __launch_bounds__(256) void wtrans_kernel(
        const float* __restrict__ W1, ushort* __restrict__ Wt1,
        const float* __restrict__ W2, ushort* __restrict__ Wt2) {
    __shared__ ushort T[64][138];
    const float* W = (blockIdx.z == 0) ? W1 : W2;
    ushort*    Wt = (blockIdx.z == 0) ? Wt1 : Wt2;
    int r  = blockIdx.y;
    int c0 = blockIdx.x * 64;
    int t  = threadIdx.x;
    int lane6 = t & 63;
    #pragma unroll
    for (int it = 0; it < 16; ++it) {
        int ch = (t >> 6) + 4 * it;
        int d  = lane6 * 2;
        float2 v = *(const float2*)&W[(((size_t)r << 10) + c0 + ch) * 128 + d];
        T[ch][d]     = f2bf(v.x);
        T[ch][d + 1] = f2bf(v.y);
    }
    __syncthreads();
    #pragma unroll
    for (int it = 0; it < 32; ++it) {
        int d = (t >> 6) + 4 * it;
        Wt[(size_t)(r * 128 + d) * 1024 + c0 + lane6] = T[lane6][d];
    }
}

// --------------------------------------------------------------------------
// Fused GEMM + aggregate.  One wg = (sample, colblock cb): computes
// P[sample rows][cb*128 .. +128] via MFMA into LDS, then aggregates
// out[n,j] = relu(sum_k w[cb][n,k] * P_lds[nbr[n,k]][j]) without HBM P.
// grid 512 = 64 samples x 8 cb (2 wg/CU).  M=100 pad 112, BK=32, dbuf.
// --------------------------------------------------------------------------
__global__ __launch_bounds__(256) void fused_gemm_agg_kernel(
        const ushort* __restrict__ Xb,    // [6400][1024] bf16 (layer input)
        const ushort* __restrict__ Wt,    // [1024][1024] bf16
        const float* __restrict__ wR,     // [R][E] edge weights
        const int*   __restrict__ nbr,    // [BN][16]
        ushort* __restrict__ outB,        // bf16 h   (layer 1) or null
        float*  __restrict__ outF) {      // fp32 out (layer 2) or null
    __shared__ ushort Asb[2][112][32];
    __shared__ ushort Bsb[2][128][32];
    __shared__ ushort P_lds[100][128];
    __shared__ float  w_lds[1600];
    __shared__ int    f_lds[1600];

    int bid = blockIdx.x;                       // 512 = 8 XCDs * 64
    int swz = (bid & 7) * 64 + (bid >> 3);      // bijective
    int sample = swz >> 3, cb = swz & 7;
    int t = threadIdx.x, wid = t >> 6, lane = t & 63;

    int srow  = lane >> 2;
    int sslot = (lane & 3) ^ ((lane >> 2) & 3) ^ (lane >> 4);
    int pslot = (lane >> 4) ^ (lane & 3) ^ ((lane >> 2) & 3);

    const ushort* agp = Xb + (size_t)(sample * 100 + srow) * 1024 + sslot * 8;
    const ushort* bgp = Wt + (size_t)(cb * 128 + srow) * 1024 + sslot * 8;

    f32x4 acc[7][2];
    #pragma unroll
    for (int i = 0; i < 7; ++i) { acc[i][0] = (f32x4)0.f; acc[i][1] = (f32x4)0.f; }

    // prologue: stage K-step 0 into buf 0
    #pragma unroll
    for (int q = 0; q < 2; ++q) {
        int ch = wid + 4 * q;
        if (ch < 7) gload_lds16(agp + (size_t)ch * 16 * 1024, &Asb[0][ch * 16][0]);
        gload_lds16(bgp + (size_t)ch * 16 * 1024, &Bsb[0][ch * 16][0]);
    }
    __syncthreads();

    for (int ts = 0; ts < 32; ++ts) {
        int cur = ts & 1;
        if (ts < 31) {
            int c1 = (ts + 1) * 32;
            #pragma unroll
            for (int q = 0; q < 2; ++q) {
                int ch = wid + 4 * q;
                if (ch < 7) gload_lds16(agp + (size_t)ch * 16 * 1024 + c1,
                                        &Asb[cur ^ 1][ch * 16][0]);
                gload_lds16(bgp + (size_t)ch * 16 * 1024 + c1,
                            &Bsb[cur ^ 1][ch * 16][0]);
            }
        }
        bf16x8 af[7], bfr[2];
        #pragma unroll
        for (int mi = 0; mi < 7; ++mi)
            af[mi] = *(const bf16x8*)&Asb[cur][mi * 16 + (lane & 15)][pslot * 8];
        #pragma unroll
        for (int ni = 0; ni < 2; ++ni)
            bfr[ni] = *(const bf16x8*)&Bsb[cur][wid * 32 + ni * 16 + (lane & 15)][pslot * 8];
        #pragma unroll
        for (int mi = 0; mi < 7; ++mi)
            #pragma unroll
            for (int ni = 0; ni < 2; ++ni)
                acc[mi][ni] = __builtin_amdgcn_mfma_f32_16x16x32_bf16(
                    af[mi], bfr[ni], acc[mi][ni], 0, 0, 0);
        __syncthreads();
    }

    // epilogue 1: acc -> P_lds (bf16, XOR-swizzled col ^ ((row>>2)&3)<<4)
    #pragma unroll
    for (int mi = 0; mi < 7; ++mi) {
        #pragma unroll
        for (int ni = 0; ni < 2; ++ni) {
            int colb = wid * 32 + ni * 16 + (lane & 15);
            #pragma unroll
            for (int q = 0; q < 4; ++q) {
                int row = mi * 16 + (lane >> 4) * 4 + q;
                if (row < 100) {
                    int phys = colb ^ (((row >> 2) & 3) << 4);
                    P_lds[row][phys] = f2bf(acc[mi][ni][q]);
                }
            }
        }
    }
    // epilogue 2: load w-slice (r = cb) + neighbor ids for this sample
    {
        const float* wsrc = wR + (size_t)cb * E_ + (size_t)sample * 1600;
        const int*   nsrc = nbr + (size_t)sample * 1600;
        for (int i = t; i < 1600; i += 256) {
            w_lds[i] = wsrc[i];
            f_lds[i] = nsrc[i];
        }
    }
    __syncthreads();

    // epilogue 3: aggregate.  thread: j-pair p = t&63, n = (t>>6) + 4i.
    int p = lane;                // j = 2p, 2p+1
    int nb = wid;
    for (int i = 0; i < 25; ++i) {
        int n = nb + 4 * i;
        float a0 = 0.f, a1 = 0.f;
        #pragma unroll
        for (int k = 0; k < 16; ++k) {
            int row  = f_lds[n * 16 + k];
            float wk = w_lds[n * 16 + k];
            ushort2 v = *(const ushort2*)&P_lds[row][(2 * p) ^ (((row >> 2) & 3) << 4)];
            a0 += wk * bf2f(v.x);
            a1 += wk * bf2f(v.y);
        }
        a0 = fmaxf(a0, 0.f);
        a1 = fmaxf(a1, 0.f);
        size_t base = (size_t)(sample * 100 + n) * 1024 + cb * 128 + 2 * p;
        if (outB) {
            ushort2 o; o.x = f2bf(a0); o.y = f2bf(a1);
            *(ushort2*)&outB[base] = o;
        } else {
            float2 o; o.x = a0; o.y = a1;
            *(float2*)&outF[base] = o;
        }
    }
}

// --------------------------------------------------------------------------
extern "C" void kernel_launch(void* const* d_in, const int* in_sizes, int n_in,
                              void* d_out, int out_size, void* d_ws, size_t ws_size,
                              hipStream_t stream) {
    const float* node_feats = (const float*)d_in[0];
    const float* centre     = (const float*)d_in[1];
    const float* graph_w    = (const float*)d_in[2];
    const int*   nbr_idx    = (const int*)  d_in[3];
    const float* mr1 = (const float*)d_in[4];
    const float* mt1 = (const float*)d_in[5];
    const float* pr1 = (const float*)d_in[6];
    const float* pt1 = (const float*)d_in[7];
    const float* cw1 = (const float*)d_in[8];
    const float* mr2 = (const float*)d_in[9];
    const float* mt2 = (const float*)d_in[10];
    const float* pr2 = (const float*)d_in[11];
    const float* pt2 = (const float*)d_in[12];
    const float* cw2 = (const float*)d_in[13];

    char* ws = (char*)d_ws;
    ushort* Xb  = (ushort*)ws;  ws += (size_t)BN_ * 1024 * 2;   // 13.1 MB
    ushort* W1t = (ushort*)ws;  ws += (size_t)1024 * 1024 * 2;  // 2 MB
    ushort* W2t = (ushort*)ws;  ws += (size_t)1024 * 1024 * 2;  // 2 MB
    ushort* hb  = (ushort*)ws;  ws += (size_t)BN_ * 1024 * 2;   // 13.1 MB
    float*  w1  = (float*)ws;   ws += (size_t)R_ * E_ * 4;      // 3.28 MB
    float*  w2  = (float*)ws;                                   // 3.28 MB

    float* out = (float*)d_out;

    edge_weights_kernel<<<(E_ + 255) / 256, 256, 0, stream>>>(
        centre, nbr_idx, graph_w, mr1, mt1, pr1, pt1, mr2, mt2, pr2, pt2, w1, w2);
    cast_x_kernel<<<BN_ * 1024 / 4 / 256, 256, 0, stream>>>(node_feats, Xb);
    wtrans_kernel<<<dim3(16, 8, 2), 256, 0, stream>>>(cw1, W1t, cw2, W2t);

    fused_gemm_agg_kernel<<<512, 256, 0, stream>>>(Xb, W1t, w1, nbr_idx, hb, nullptr);
    fused_gemm_agg_kernel<<<512, 256, 0, stream>>>(hb, W2t, w2, nbr_idx, nullptr, out);
}